// Round 1
// baseline (408.851 us; speedup 1.0000x reference)
//
#include <hip/hip_runtime.h>

// ---- problem constants ----
#define Bb_ 2
#define S_ 2048
#define D_ 512
#define H_ 8
#define DH_ 64
#define ROWS_ 4096   // B*S

typedef __attribute__((ext_vector_type(8))) __bf16 bf16x8;
typedef __attribute__((ext_vector_type(4))) __bf16 bf16x4;
typedef __attribute__((ext_vector_type(4))) float f32x4;
typedef __attribute__((ext_vector_type(8))) short short8;

// ---------------- weight transpose + bf16 convert ----------------
// w: (K,N) fp32 -> wt: (N,K) bf16.  Reads coalesced; scattered 2B writes (small).
__global__ __launch_bounds__(256) void wtrans_kernel(const float* __restrict__ w,
                                                     __bf16* __restrict__ wt,
                                                     int K, int N) {
  int idx = blockIdx.x * 256 + threadIdx.x;
  if (idx >= K * N) return;
  int k = idx / N, n = idx - k * N;
  wt[(long)n * K + k] = (__bf16)w[idx];
}

// ---------------- layernorm (ddof=0), row length 512 ----------------
__global__ __launch_bounds__(256) void ln_kernel(const float* __restrict__ x,
                                                 const float* __restrict__ w,
                                                 const float* __restrict__ b,
                                                 __bf16* __restrict__ out) {
  long row = blockIdx.x;
  const float* xr = x + row * 512;
  int t = threadIdx.x;
  float2 v = *reinterpret_cast<const float2*>(xr + t * 2);
  float s = v.x + v.y;
  float sq = v.x * v.x + v.y * v.y;
#pragma unroll
  for (int m = 1; m < 64; m <<= 1) {
    s += __shfl_xor(s, m);
    sq += __shfl_xor(sq, m);
  }
  __shared__ float red[8];
  int wid = t >> 6;
  if ((t & 63) == 0) { red[wid] = s; red[wid + 4] = sq; }
  __syncthreads();
  s = red[0] + red[1] + red[2] + red[3];
  sq = red[4] + red[5] + red[6] + red[7];
  float mu = s * (1.f / 512.f);
  float var = sq * (1.f / 512.f) - mu * mu;  // ddof=0
  float rs = rsqrtf(var + 1e-5f);
  int c = t * 2;
  float o0 = (v.x - mu) * rs * w[c] + b[c];
  float o1 = (v.y - mu) * rs * w[c + 1] + b[c + 1];
  __bf16* op = out + row * 512 + c;
  op[0] = (__bf16)o0;
  op[1] = (__bf16)o1;
}

// ---------------- generic bf16 MFMA GEMM ----------------
// C(M,N) = act(A(M,K) @ Bt(N,K)^T + bias [+ res]) , 128x128 tile, BK=64,
// 4 waves in 2x2, each wave 64x64 = 4x4 frags of 16x16 (mfma_f32_16x16x32_bf16).
// OUTMODE: 0 = fp32 out (outF, + z*cSZ), 1 = bf16 out (outB),
//          2 = qkv scatter: cols<1024 -> outB (4096x1024), cols>=1024 -> Vt (B,H,64,S)
// ACT: 0 none, 1 relu, 2 gelu(exact)
template <int ACT, int OUTMODE, bool HASRES>
__global__ __launch_bounds__(256) void gemm_kernel(
    const __bf16* __restrict__ A, const __bf16* __restrict__ Bt,
    const float* __restrict__ bias, const float* __restrict__ res,
    float* __restrict__ outF, __bf16* __restrict__ outB, __bf16* __restrict__ outVt,
    int lda, int ldb, int ldc, int K,
    long aSB, int aSH, long bSB, int bSH, long cSZ) {
  __shared__ __align__(16) __bf16 As[128 * 64];
  __shared__ __align__(16) __bf16 Bs[128 * 64];
  int t = threadIdx.x, lane = t & 63, wid = t >> 6;
  int z = blockIdx.z, zb = z >> 3, zh = z & 7;
  const __bf16* Ab = A + zb * aSB + (long)zh * aSH + (long)blockIdx.y * 128 * lda;
  const __bf16* Bb = Bt + zb * bSB + (long)zh * bSH + (long)blockIdx.x * 128 * ldb;

  f32x4 acc[4][4];
#pragma unroll
  for (int i = 0; i < 4; i++)
#pragma unroll
    for (int j = 0; j < 4; j++) acc[i][j] = (f32x4){0.f, 0.f, 0.f, 0.f};

  int wr = wid >> 1, wc = wid & 1;
  int kq = lane >> 4;  // 0..3

  for (int k0 = 0; k0 < K; k0 += 64) {
    __syncthreads();  // protect LDS from previous iteration's readers
    // stage both tiles: chunk = 16B (8 bf16). 1024 chunks/tile, 4 per thread.
    // LDS[row][c] = G[row][c ^ (row&7)]  (XOR swizzle; conflict-free frag reads)
#pragma unroll
    for (int i = 0; i < 4; i++) {
      int ci = i * 256 + t;      // 0..1023, lanes write consecutive 16B chunks
      int row = ci >> 3;         // 0..127
      int c = ci & 7;
      int sc = c ^ (row & 7);
      short8 va = *reinterpret_cast<const short8*>(Ab + (long)row * lda + k0 + sc * 8);
      *reinterpret_cast<short8*>(&As[row * 64 + c * 8]) = va;
      short8 vb = *reinterpret_cast<const short8*>(Bb + (long)row * ldb + k0 + sc * 8);
      *reinterpret_cast<short8*>(&Bs[row * 64 + c * 8]) = vb;
    }
    __syncthreads();
#pragma unroll
    for (int ks = 0; ks < 2; ks++) {
      bf16x8 af[4], bfr[4];
#pragma unroll
      for (int fm = 0; fm < 4; fm++) {
        int r = wr * 64 + fm * 16 + (lane & 15);
        int c = (ks * 4 + kq) ^ (r & 7);
        af[fm] = *reinterpret_cast<const bf16x8*>(&As[r * 64 + c * 8]);
      }
#pragma unroll
      for (int fn = 0; fn < 4; fn++) {
        int r = wc * 64 + fn * 16 + (lane & 15);
        int c = (ks * 4 + kq) ^ (r & 7);
        bfr[fn] = *reinterpret_cast<const bf16x8*>(&Bs[r * 64 + c * 8]);
      }
#pragma unroll
      for (int fm = 0; fm < 4; fm++)
#pragma unroll
        for (int fn = 0; fn < 4; fn++)
          acc[fm][fn] = __builtin_amdgcn_mfma_f32_16x16x32_bf16(af[fm], bfr[fn],
                                                                acc[fm][fn], 0, 0, 0);
    }
  }

  // epilogue: C elem (reg r4): row = (lane>>4)*4 + r4, col = lane&15  [m89]
  long gr0 = (long)blockIdx.y * 128 + wr * 64;
  long gc0 = (long)blockIdx.x * 128 + wc * 64;
#pragma unroll
  for (int fm = 0; fm < 4; fm++)
#pragma unroll
    for (int fn = 0; fn < 4; fn++) {
      int col = (int)gc0 + fn * 16 + (lane & 15);
      long rbase = gr0 + fm * 16 + kq * 4;
      float bv = bias ? bias[col] : 0.f;
#pragma unroll
      for (int r4 = 0; r4 < 4; r4++) {
        long grow = rbase + r4;
        float v = acc[fm][fn][r4] + bv;
        if (HASRES) v += res[grow * ldc + col];
        if (ACT == 1) v = fmaxf(v, 0.f);
        if (ACT == 2) v = 0.5f * v * (1.f + erff(v * 0.70710678118f));
        if (OUTMODE == 0) {
          outF[grow * ldc + col + z * cSZ] = v;
        } else if (OUTMODE == 1) {
          outB[grow * ldc + col] = (__bf16)v;
        } else {
          if (col < 1024) {
            outB[grow * 1024 + col] = (__bf16)v;  // Q,K natural
          } else {
            int dh = col - 1024;
            int h = dh >> 6, d = dh & 63;
            long bb = grow >> 11;
            long srow = grow & 2047;
            outVt[(((bb * 8 + h) * 64 + d) << 11) + srow] = (__bf16)v;  // V transposed
          }
        }
      }
    }
}

// ---------------- fused map_norm + sinmax + PV ----------------
// One block = 16 q-rows of one (b,h). Reads raw qk fp32 (in d_out scores area),
// writes normalized scores fp32 in place, computes hv = scores @ V via MFMA.
__global__ __launch_bounds__(256) void sinmax_pv_kernel(float* __restrict__ sco,
                                                        const __bf16* __restrict__ vt,
                                                        __bf16* __restrict__ hv) {
  __shared__ __align__(16) __bf16 s_lds[16 * 2048];  // exactly 64KB, XOR-swizzled
  int bid = blockIdx.x;            // 0..2047
  int q0 = (bid & 127) << 4;       // 128 blocks per head
  int hh = (bid >> 7) & 7;
  int bb = bid >> 10;
  float* srow = sco + (((long)(bb * 8 + hh)) * 2048 + q0) * 2048;
  const __bf16* vtb = vt + ((long)(bb * 8 + hh)) * 64 * 2048;
  int t = threadIdx.x, lane = t & 63;
  int row = t >> 4, g = t & 15;    // 16 threads per q-row (same wave)
  float* rp = srow + (long)row * 2048;

  // phase 1: row stats (ddof=1)
  float sum = 0.f, sq = 0.f;
#pragma unroll
  for (int j = 0; j < 32; j++) {
    float4 v = *reinterpret_cast<const float4*>(rp + (j * 16 + g) * 4);
    sum += v.x + v.y + v.z + v.w;
    sq += v.x * v.x + v.y * v.y + v.z * v.z + v.w * v.w;
  }
#pragma unroll
  for (int m = 1; m < 16; m <<= 1) {
    sum += __shfl_xor(sum, m);
    sq += __shfl_xor(sq, m);
  }
  float mu = sum * (1.f / 2048.f);
  float var = (sq - 2048.f * mu * mu) * (1.f / 2047.f);
  float rs = rsqrtf(var + 1e-5f);

  // phase 2: s = 1 + sin(1.25 * (qk-mu)*rs)  -> bf16 LDS (swizzled), row sum
  float rsum = 0.f;
  char* ldsb = reinterpret_cast<char*>(s_lds) + row * 4096;
#pragma unroll
  for (int j = 0; j < 32; j++) {
    int col = (j * 16 + g) * 4;
    float4 v = *reinterpret_cast<const float4*>(rp + col);
    float s0 = 1.f + __sinf(1.25f * (v.x - mu) * rs);
    float s1 = 1.f + __sinf(1.25f * (v.y - mu) * rs);
    float s2 = 1.f + __sinf(1.25f * (v.z - mu) * rs);
    float s3 = 1.f + __sinf(1.25f * (v.w - mu) * rs);
    rsum += s0 + s1 + s2 + s3;
    bf16x4 sv;
    sv[0] = (__bf16)s0; sv[1] = (__bf16)s1; sv[2] = (__bf16)s2; sv[3] = (__bf16)s3;
    int boff = (col * 2) ^ ((row & 7) << 4);
    *reinterpret_cast<bf16x4*>(ldsb + boff) = sv;
  }
#pragma unroll
  for (int m = 1; m < 16; m <<= 1) rsum += __shfl_xor(rsum, m);
  float inv = 1.f / rsum;

  // phase 3: write normalized scores fp32 (in place), normalize LDS copy
#pragma unroll
  for (int j = 0; j < 32; j++) {
    int col = (j * 16 + g) * 4;
    int boff = (col * 2) ^ ((row & 7) << 4);
    bf16x4 sv = *reinterpret_cast<const bf16x4*>(ldsb + boff);
    float4 o;
    o.x = (float)sv[0] * inv;
    o.y = (float)sv[1] * inv;
    o.z = (float)sv[2] * inv;
    o.w = (float)sv[3] * inv;
    *reinterpret_cast<float4*>(rp + col) = o;
    bf16x4 nv;
    nv[0] = (__bf16)o.x; nv[1] = (__bf16)o.y; nv[2] = (__bf16)o.z; nv[3] = (__bf16)o.w;
    *reinterpret_cast<bf16x4*>(ldsb + boff) = nv;
  }
  __syncthreads();

  // phase 4: hv(16 x 64) = scores(16 x 2048) @ V(2048 x 64), wave w -> d-block w*16
  int wid2 = t >> 6;
  int colq = lane & 15;
  int kq = lane >> 4;
  f32x4 pacc = (f32x4){0.f, 0.f, 0.f, 0.f};
  const __bf16* vbase = vtb + (long)(wid2 * 16 + colq) * 2048;  // Vt row = d
  const char* ldsa = reinterpret_cast<const char*>(s_lds);
  int r = lane & 15;
#pragma unroll 4
  for (int ks = 0; ks < 64; ks++) {
    int kb = (ks * 32 + kq * 8) * 2;
    int boff = kb ^ ((r & 7) << 4);
    bf16x8 af = *reinterpret_cast<const bf16x8*>(ldsa + r * 4096 + boff);
    bf16x8 bv = *reinterpret_cast<const bf16x8*>(vbase + ks * 32 + kq * 8);
    pacc = __builtin_amdgcn_mfma_f32_16x16x32_bf16(af, bv, pacc, 0, 0, 0);
  }
#pragma unroll
  for (int r4 = 0; r4 < 4; r4++) {
    int qr = kq * 4 + r4;
    hv[((long)(bb * 2048) + q0 + qr) * 512 + hh * 64 + wid2 * 16 + colq] = (__bf16)pacc[r4];
  }
}

// ---------------- launch ----------------
extern "C" void kernel_launch(void* const* d_in, const int* in_sizes, int n_in,
                              void* d_out, int out_size, void* d_ws, size_t ws_size,
                              hipStream_t stream) {
  const float* x = (const float*)d_in[0];
  const float* norm_w = (const float*)d_in[1];
  const float* norm_b = (const float*)d_in[2];
  const float* qvk_w = (const float*)d_in[3];
  const float* qvk_b = (const float*)d_in[4];
  const float* concat_w = (const float*)d_in[5];
  const float* concat_b = (const float*)d_in[6];
  const float* mlp_norm_w = (const float*)d_in[7];
  const float* mlp_norm_b = (const float*)d_in[8];
  const float* mlp1_w = (const float*)d_in[9];
  const float* mlp1_b = (const float*)d_in[10];
  const float* mlp2_w = (const float*)d_in[11];
  const float* mlp2_b = (const float*)d_in[12];

  char* ws = (char*)d_ws;
  __bf16* qvk_wT = (__bf16*)(ws + 0);          // 1536x512 bf16
  __bf16* concat_wT = (__bf16*)(ws + 1572864); // 512x512
  __bf16* mlp1_wT = (__bf16*)(ws + 2097152);   // 1024x512
  __bf16* mlp2_wT = (__bf16*)(ws + 3145728);   // 512x1024
  __bf16* xn = (__bf16*)(ws + 4194304);        // 4096x512
  __bf16* qk_buf = (__bf16*)(ws + 8388608);    // 4096x1024 (Q|K)
  __bf16* vt = (__bf16*)(ws + 16777216);       // (B,H,64,2048)
  __bf16* hv = (__bf16*)(ws + 20971520);       // 4096x512
  float* attout = (float*)(ws + 25165824);     // 4096x512 fp32
  __bf16* a_b = (__bf16*)(ws + 33554432);      // 4096x512
  __bf16* h_b = (__bf16*)(ws + 37748736);      // 4096x1024

  float* out0 = (float*)d_out;
  float* sco = out0 + 2097152;  // scores region (B,H,S,S) fp32

  wtrans_kernel<<<3072, 256, 0, stream>>>(qvk_w, qvk_wT, 512, 1536);
  wtrans_kernel<<<1024, 256, 0, stream>>>(concat_w, concat_wT, 512, 512);
  wtrans_kernel<<<2048, 256, 0, stream>>>(mlp1_w, mlp1_wT, 512, 1024);
  wtrans_kernel<<<2048, 256, 0, stream>>>(mlp2_w, mlp2_wT, 1024, 512);

  ln_kernel<<<4096, 256, 0, stream>>>(x, norm_w, norm_b, xn);

  // qkv = relu(xn @ qvk_w + b); Q,K natural -> qk_buf, V transposed -> vt
  gemm_kernel<1, 2, false><<<dim3(12, 32, 1), 256, 0, stream>>>(
      xn, qvk_wT, qvk_b, nullptr, nullptr, qk_buf, vt,
      512, 512, 1536, 512, 0, 0, 0, 0, 0);

  // raw qk = Q @ K^T per (b,h) -> scores region (fp32, overwritten by sinmax)
  gemm_kernel<0, 0, false><<<dim3(16, 16, 16), 256, 0, stream>>>(
      qk_buf, qk_buf + 512, nullptr, nullptr, sco, nullptr, nullptr,
      1024, 1024, 2048, 64,
      (long)2048 * 1024, 64, (long)2048 * 1024, 64, (long)2048 * 2048);

  sinmax_pv_kernel<<<2048, 256, 0, stream>>>(sco, vt, hv);

  // attout = hv @ concat_w + b + x  (fp32)
  gemm_kernel<0, 0, true><<<dim3(4, 32, 1), 256, 0, stream>>>(
      hv, concat_wT, concat_b, x, attout, nullptr, nullptr,
      512, 512, 512, 512, 0, 0, 0, 0, 0);

  ln_kernel<<<4096, 256, 0, stream>>>(attout, mlp_norm_w, mlp_norm_b, a_b);

  // h = gelu(a @ mlp1_w + b)
  gemm_kernel<2, 1, false><<<dim3(8, 32, 1), 256, 0, stream>>>(
      a_b, mlp1_wT, mlp1_b, nullptr, nullptr, h_b, nullptr,
      512, 512, 1024, 512, 0, 0, 0, 0, 0);

  // out0 = h @ mlp2_w + b + attout (fp32)
  gemm_kernel<0, 0, true><<<dim3(4, 32, 1), 256, 0, stream>>>(
      h_b, mlp2_wT, mlp2_b, attout, out0, nullptr, nullptr,
      1024, 1024, 512, 1024, 0, 0, 0, 0, 0);
}

// Round 2
// 300.316 us; speedup vs baseline: 1.3614x; 1.3614x over previous
//
#include <hip/hip_runtime.h>

// ---- problem constants ----
#define Bb_ 2
#define S_ 2048
#define D_ 512
#define H_ 8
#define DH_ 64
#define ROWS_ 4096   // B*S

typedef __attribute__((ext_vector_type(8))) __bf16 bf16x8;
typedef __attribute__((ext_vector_type(4))) __bf16 bf16x4;
typedef __attribute__((ext_vector_type(2))) __bf16 bf16x2;
typedef __attribute__((ext_vector_type(4))) float f32x4;
typedef __attribute__((ext_vector_type(8))) short short8;

// ---------------- weight transpose + bf16 convert ----------------
__global__ __launch_bounds__(256) void wtrans_kernel(const float* __restrict__ w,
                                                     __bf16* __restrict__ wt,
                                                     int K, int N) {
  int idx = blockIdx.x * 256 + threadIdx.x;
  if (idx >= K * N) return;
  int k = idx / N, n = idx - k * N;
  wt[(long)n * K + k] = (__bf16)w[idx];
}

// ---------------- layernorm (ddof=0), row length 512 ----------------
__global__ __launch_bounds__(256) void ln_kernel(const float* __restrict__ x,
                                                 const float* __restrict__ w,
                                                 const float* __restrict__ b,
                                                 __bf16* __restrict__ out) {
  long row = blockIdx.x;
  const float* xr = x + row * 512;
  int t = threadIdx.x;
  float2 v = *reinterpret_cast<const float2*>(xr + t * 2);
  float s = v.x + v.y;
  float sq = v.x * v.x + v.y * v.y;
#pragma unroll
  for (int m = 1; m < 64; m <<= 1) {
    s += __shfl_xor(s, m);
    sq += __shfl_xor(sq, m);
  }
  __shared__ float red[8];
  int wid = t >> 6;
  if ((t & 63) == 0) { red[wid] = s; red[wid + 4] = sq; }
  __syncthreads();
  s = red[0] + red[1] + red[2] + red[3];
  sq = red[4] + red[5] + red[6] + red[7];
  float mu = s * (1.f / 512.f);
  float var = sq * (1.f / 512.f) - mu * mu;  // ddof=0
  float rs = rsqrtf(var + 1e-5f);
  int c = t * 2;
  float o0 = (v.x - mu) * rs * w[c] + b[c];
  float o1 = (v.y - mu) * rs * w[c + 1] + b[c + 1];
  __bf16* op = out + row * 512 + c;
  op[0] = (__bf16)o0;
  op[1] = (__bf16)o1;
}

// ---------------- generic bf16 MFMA GEMM ----------------
// C(M,N) = act(A(M,K) @ Bt(N,K)^T + bias [+ res]), 128x128 tile, BK=64.
// OUTMODE: 0 = fp32 out (outF), 1 = bf16 out (outB),
//          2 = qkv scatter: cols<1024 -> outB (Q|K), cols>=1024 -> Vt (B,H,64,S)
// ACT: 0 none, 1 relu, 2 gelu(exact)
template <int ACT, int OUTMODE, bool HASRES>
__global__ __launch_bounds__(256) void gemm_kernel(
    const __bf16* __restrict__ A, const __bf16* __restrict__ Bt,
    const float* __restrict__ bias, const float* __restrict__ res,
    float* __restrict__ outF, __bf16* __restrict__ outB, __bf16* __restrict__ outVt,
    int lda, int ldb, int ldc, int K) {
  __shared__ __align__(16) __bf16 As[128 * 64];
  __shared__ __align__(16) __bf16 Bs[128 * 64];
  int t = threadIdx.x, lane = t & 63, wid = t >> 6;
  const __bf16* Ab = A + (long)blockIdx.y * 128 * lda;
  const __bf16* Bb = Bt + (long)blockIdx.x * 128 * ldb;

  f32x4 acc[4][4];
#pragma unroll
  for (int i = 0; i < 4; i++)
#pragma unroll
    for (int j = 0; j < 4; j++) acc[i][j] = (f32x4){0.f, 0.f, 0.f, 0.f};

  int wr = wid >> 1, wc = wid & 1;
  int kq = lane >> 4;  // 0..3

  for (int k0 = 0; k0 < K; k0 += 64) {
    __syncthreads();
#pragma unroll
    for (int i = 0; i < 4; i++) {
      int ci = i * 256 + t;      // 0..1023
      int row = ci >> 3;         // 0..127
      int c = ci & 7;
      int sc = c ^ (row & 7);
      short8 va = *reinterpret_cast<const short8*>(Ab + (long)row * lda + k0 + sc * 8);
      *reinterpret_cast<short8*>(&As[row * 64 + c * 8]) = va;
      short8 vb = *reinterpret_cast<const short8*>(Bb + (long)row * ldb + k0 + sc * 8);
      *reinterpret_cast<short8*>(&Bs[row * 64 + c * 8]) = vb;
    }
    __syncthreads();
#pragma unroll
    for (int ks = 0; ks < 2; ks++) {
      bf16x8 af[4], bfr[4];
#pragma unroll
      for (int fm = 0; fm < 4; fm++) {
        int r = wr * 64 + fm * 16 + (lane & 15);
        int c = (ks * 4 + kq) ^ (r & 7);
        af[fm] = *reinterpret_cast<const bf16x8*>(&As[r * 64 + c * 8]);
      }
#pragma unroll
      for (int fn = 0; fn < 4; fn++) {
        int r = wc * 64 + fn * 16 + (lane & 15);
        int c = (ks * 4 + kq) ^ (r & 7);
        bfr[fn] = *reinterpret_cast<const bf16x8*>(&Bs[r * 64 + c * 8]);
      }
#pragma unroll
      for (int fm = 0; fm < 4; fm++)
#pragma unroll
        for (int fn = 0; fn < 4; fn++)
          acc[fm][fn] = __builtin_amdgcn_mfma_f32_16x16x32_bf16(af[fm], bfr[fn],
                                                                acc[fm][fn], 0, 0, 0);
    }
  }

  long gr0 = (long)blockIdx.y * 128 + wr * 64;
  long gc0 = (long)blockIdx.x * 128 + wc * 64;
#pragma unroll
  for (int fm = 0; fm < 4; fm++)
#pragma unroll
    for (int fn = 0; fn < 4; fn++) {
      int col = (int)gc0 + fn * 16 + (lane & 15);
      long rbase = gr0 + fm * 16 + kq * 4;
      float bv = bias ? bias[col] : 0.f;
#pragma unroll
      for (int r4 = 0; r4 < 4; r4++) {
        long grow = rbase + r4;
        float v = acc[fm][fn][r4] + bv;
        if (HASRES) v += res[grow * ldc + col];
        if (ACT == 1) v = fmaxf(v, 0.f);
        if (ACT == 2) v = 0.5f * v * (1.f + erff(v * 0.70710678118f));
        if (OUTMODE == 0) {
          outF[grow * ldc + col] = v;
        } else if (OUTMODE == 1) {
          outB[grow * ldc + col] = (__bf16)v;
        } else {
          if (col < 1024) {
            outB[grow * 1024 + col] = (__bf16)v;  // Q,K natural
          } else {
            int dh = col - 1024;
            int h = dh >> 6, d = dh & 63;
            long bb = grow >> 11;
            long srow = grow & 2047;
            outVt[(((bb * 8 + h) * 64 + d) << 11) + srow] = (__bf16)v;  // V transposed
          }
        }
      }
    }
}

// ---------------- fused QK^T + map_norm + sinmax + scores + PV ----------------
// Block = 16 q-rows of one (b,h). 4 waves; wave w owns k-cols [w*512, w*512+512).
// QK via MFMA (K B-frags direct from global), stats via shfl+LDS, sin in regs,
// normalized scores -> bf16 LDS (XOR swizzle) -> coalesced fp32 store + PV MFMA.
__global__ __launch_bounds__(256, 2) void fused_attn_kernel(
    const __bf16* __restrict__ qk_buf, const __bf16* __restrict__ vt,
    float* __restrict__ sco, __bf16* __restrict__ hv) {
  __shared__ __align__(16) __bf16 s_lds[16 * 2048];  // 64KB swizzled bf16 scores
  __shared__ float red_s[4][16];
  __shared__ float red_q[4][16];
  __shared__ float red2[4][16];

  // XCD-aware swizzle: 2048 blocks, XCD k gets heads {2k, 2k+1} (1MB K+V in L2)
  int bid = blockIdx.x;
  int xcd = bid & 7, jj0 = bid >> 3;
  int head = xcd * 2 + (jj0 >> 7);   // 0..15 = bb*8+hh
  int sub = jj0 & 127;
  int bb = head >> 3, hh = head & 7;
  int q0 = sub << 4;

  int t = threadIdx.x, lane = t & 63, wv = t >> 6;
  int cg = lane >> 4, ln = lane & 15;

  const __bf16* Qb = qk_buf + (long)(bb * 2048 + q0) * 1024 + hh * 64;
  const __bf16* Kb = qk_buf + (long)bb * 2048 * 1024 + 512 + hh * 64;

  // A-frags: Q rows (lane&15), k-elems cg*8 within each 32-k step
  bf16x8 qf0 = *reinterpret_cast<const bf16x8*>(Qb + ln * 1024 + cg * 8);
  bf16x8 qf1 = *reinterpret_cast<const bf16x8*>(Qb + ln * 1024 + 32 + cg * 8);

  f32x4 acc[32];
#pragma unroll
  for (int nt = 0; nt < 32; nt++) acc[nt] = (f32x4){0.f, 0.f, 0.f, 0.f};

  // ---- QK^T: 64 MFMA per wave, K loaded direct (16B/lane, L2-resident) ----
  const __bf16* Kw = Kb + (long)(wv * 512 + ln) * 1024 + cg * 8;
#pragma unroll
  for (int nt = 0; nt < 32; nt++) {
    bf16x8 k0 = *reinterpret_cast<const bf16x8*>(Kw + (long)nt * 16 * 1024);
    bf16x8 k1 = *reinterpret_cast<const bf16x8*>(Kw + (long)nt * 16 * 1024 + 32);
    acc[nt] = __builtin_amdgcn_mfma_f32_16x16x32_bf16(qf0, k0, acc[nt], 0, 0, 0);
    acc[nt] = __builtin_amdgcn_mfma_f32_16x16x32_bf16(qf1, k1, acc[nt], 0, 0, 0);
  }
  // acc[nt][r4]: qk at q-row (q0 + cg*4 + r4), k-col (wv*512 + nt*16 + ln)

  // ---- row stats (full 2048-row, ddof=1) ----
  float ss[4] = {0.f, 0.f, 0.f, 0.f}, qq[4] = {0.f, 0.f, 0.f, 0.f};
#pragma unroll
  for (int nt = 0; nt < 32; nt++)
#pragma unroll
    for (int r4 = 0; r4 < 4; r4++) {
      float v = acc[nt][r4];
      ss[r4] += v;
      qq[r4] += v * v;
    }
#pragma unroll
  for (int r4 = 0; r4 < 4; r4++)
#pragma unroll
    for (int m = 1; m < 16; m <<= 1) {
      ss[r4] += __shfl_xor(ss[r4], m);
      qq[r4] += __shfl_xor(qq[r4], m);
    }
  if (ln == 0) {
#pragma unroll
    for (int r4 = 0; r4 < 4; r4++) {
      red_s[wv][cg * 4 + r4] = ss[r4];
      red_q[wv][cg * 4 + r4] = qq[r4];
    }
  }
  __syncthreads();
  float mu[4], rs[4];
#pragma unroll
  for (int r4 = 0; r4 < 4; r4++) {
    int r = cg * 4 + r4;
    float s = red_s[0][r] + red_s[1][r] + red_s[2][r] + red_s[3][r];
    float sq = red_q[0][r] + red_q[1][r] + red_q[2][r] + red_q[3][r];
    mu[r4] = s * (1.f / 2048.f);
    float var = (sq - 2048.f * mu[r4] * mu[r4]) * (1.f / 2047.f);
    rs[r4] = rsqrtf(var + 1e-5f);
  }

  // ---- sinmax numerator in regs + denominator reduce ----
  float rsum[4] = {0.f, 0.f, 0.f, 0.f};
#pragma unroll
  for (int nt = 0; nt < 32; nt++)
#pragma unroll
    for (int r4 = 0; r4 < 4; r4++) {
      float p = 1.f + __sinf(1.25f * (acc[nt][r4] - mu[r4]) * rs[r4]);
      acc[nt][r4] = p;
      rsum[r4] += p;
    }
#pragma unroll
  for (int r4 = 0; r4 < 4; r4++)
#pragma unroll
    for (int m = 1; m < 16; m <<= 1) rsum[r4] += __shfl_xor(rsum[r4], m);
  if (ln == 0) {
#pragma unroll
    for (int r4 = 0; r4 < 4; r4++) red2[wv][cg * 4 + r4] = rsum[r4];
  }
  __syncthreads();
  float inv[4];
#pragma unroll
  for (int r4 = 0; r4 < 4; r4++) {
    int r = cg * 4 + r4;
    inv[r4] = 1.f / (red2[0][r] + red2[1][r] + red2[2][r] + red2[3][r]);
  }

  // ---- normalized scores -> bf16 LDS (pairs packed via shfl; XOR swizzle) ----
  char* ldsb = reinterpret_cast<char*>(s_lds);
#pragma unroll
  for (int nt = 0; nt < 32; nt++)
#pragma unroll
    for (int r4 = 0; r4 < 4; r4++) {
      float v = acc[nt][r4] * inv[r4];
      float v1 = __shfl_xor(v, 1);
      if ((ln & 1) == 0) {
        int col = wv * 512 + nt * 16 + ln;  // even
        int row = cg * 4 + r4;
        int boff = (col * 2) ^ ((row & 7) << 4);
        bf16x2 pv2;
        pv2[0] = (__bf16)v;
        pv2[1] = (__bf16)v1;
        *reinterpret_cast<bf16x2*>(ldsb + row * 4096 + boff) = pv2;
      }
    }
  __syncthreads();

  // ---- coalesced fp32 scores write (out1), from LDS ----
  {
    int prow = t >> 4, pg = t & 15;
    const char* ldsr = reinterpret_cast<const char*>(s_lds) + prow * 4096;
    float* srow = sco + ((long)head * 2048 + q0 + prow) * 2048;
#pragma unroll
    for (int j = 0; j < 16; j++) {
      int chunk = pg + j * 16;  // 0..255 (16B chunks of the row)
      int boff = (chunk * 16) ^ ((prow & 7) << 4);
      bf16x8 v = *reinterpret_cast<const bf16x8*>(ldsr + boff);
      float4 o0, o1;
      o0.x = (float)v[0]; o0.y = (float)v[1]; o0.z = (float)v[2]; o0.w = (float)v[3];
      o1.x = (float)v[4]; o1.y = (float)v[5]; o1.z = (float)v[6]; o1.w = (float)v[7];
      *reinterpret_cast<float4*>(srow + chunk * 8) = o0;
      *reinterpret_cast<float4*>(srow + chunk * 8 + 4) = o1;
    }
  }

  // ---- PV: hv(16x64) = scores(16x2048) @ V ; wave w -> d-block w*16 ----
  {
    const __bf16* vtb = vt + (long)head * 64 * 2048;
    f32x4 pacc = (f32x4){0.f, 0.f, 0.f, 0.f};
    const __bf16* vbase = vtb + (long)(wv * 16 + ln) * 2048;  // Vt row = d
    const char* ldsa = reinterpret_cast<const char*>(s_lds);
    int r = ln;
#pragma unroll 4
    for (int ks = 0; ks < 64; ks++) {
      int kb = (ks * 32 + cg * 8) * 2;
      int boff = kb ^ ((r & 7) << 4);
      bf16x8 af = *reinterpret_cast<const bf16x8*>(ldsa + r * 4096 + boff);
      bf16x8 bv = *reinterpret_cast<const bf16x8*>(vbase + ks * 32 + cg * 8);
      pacc = __builtin_amdgcn_mfma_f32_16x16x32_bf16(af, bv, pacc, 0, 0, 0);
    }
#pragma unroll
    for (int r4 = 0; r4 < 4; r4++) {
      int qr = cg * 4 + r4;
      hv[((long)(bb * 2048) + q0 + qr) * 512 + hh * 64 + wv * 16 + ln] = (__bf16)pacc[r4];
    }
  }
}

// ---------------- launch ----------------
extern "C" void kernel_launch(void* const* d_in, const int* in_sizes, int n_in,
                              void* d_out, int out_size, void* d_ws, size_t ws_size,
                              hipStream_t stream) {
  const float* x = (const float*)d_in[0];
  const float* norm_w = (const float*)d_in[1];
  const float* norm_b = (const float*)d_in[2];
  const float* qvk_w = (const float*)d_in[3];
  const float* qvk_b = (const float*)d_in[4];
  const float* concat_w = (const float*)d_in[5];
  const float* concat_b = (const float*)d_in[6];
  const float* mlp_norm_w = (const float*)d_in[7];
  const float* mlp_norm_b = (const float*)d_in[8];
  const float* mlp1_w = (const float*)d_in[9];
  const float* mlp1_b = (const float*)d_in[10];
  const float* mlp2_w = (const float*)d_in[11];
  const float* mlp2_b = (const float*)d_in[12];

  char* ws = (char*)d_ws;
  __bf16* qvk_wT = (__bf16*)(ws + 0);          // 1536x512 bf16
  __bf16* concat_wT = (__bf16*)(ws + 1572864); // 512x512
  __bf16* mlp1_wT = (__bf16*)(ws + 2097152);   // 1024x512
  __bf16* mlp2_wT = (__bf16*)(ws + 3145728);   // 512x1024
  __bf16* xn = (__bf16*)(ws + 4194304);        // 4096x512
  __bf16* qk_buf = (__bf16*)(ws + 8388608);    // 4096x1024 (Q|K)
  __bf16* vt = (__bf16*)(ws + 16777216);       // (B,H,64,2048)
  __bf16* hv = (__bf16*)(ws + 20971520);       // 4096x512
  float* attout = (float*)(ws + 25165824);     // 4096x512 fp32
  __bf16* a_b = (__bf16*)(ws + 33554432);      // 4096x512
  __bf16* h_b = (__bf16*)(ws + 37748736);      // 4096x1024

  float* out0 = (float*)d_out;
  float* sco = out0 + 2097152;  // scores (B,H,S,S) fp32

  wtrans_kernel<<<3072, 256, 0, stream>>>(qvk_w, qvk_wT, 512, 1536);
  wtrans_kernel<<<1024, 256, 0, stream>>>(concat_w, concat_wT, 512, 512);
  wtrans_kernel<<<2048, 256, 0, stream>>>(mlp1_w, mlp1_wT, 512, 1024);
  wtrans_kernel<<<2048, 256, 0, stream>>>(mlp2_w, mlp2_wT, 1024, 512);

  ln_kernel<<<4096, 256, 0, stream>>>(x, norm_w, norm_b, xn);

  // qkv = relu(xn @ qvk_w + b); Q,K natural -> qk_buf, V transposed -> vt
  gemm_kernel<1, 2, false><<<dim3(12, 32), 256, 0, stream>>>(
      xn, qvk_wT, qvk_b, nullptr, nullptr, qk_buf, vt, 512, 512, 1536, 512);

  // fused attention: QK^T + map_norm + sinmax (scores -> out1) + PV
  fused_attn_kernel<<<2048, 256, 0, stream>>>(qk_buf, vt, sco, hv);

  // attout = hv @ concat_w + b + x  (fp32)
  gemm_kernel<0, 0, true><<<dim3(4, 32), 256, 0, stream>>>(
      hv, concat_wT, concat_b, x, attout, nullptr, nullptr, 512, 512, 512, 512);

  ln_kernel<<<4096, 256, 0, stream>>>(attout, mlp_norm_w, mlp_norm_b, a_b);

  // h = gelu(a @ mlp1_w + b)
  gemm_kernel<2, 1, false><<<dim3(8, 32), 256, 0, stream>>>(
      a_b, mlp1_wT, mlp1_b, nullptr, nullptr, h_b, nullptr, 512, 512, 1024, 512);

  // out0 = h @ mlp2_w + b + attout (fp32)
  gemm_kernel<0, 0, true><<<dim3(4, 32), 256, 0, stream>>>(
      h_b, mlp2_wT, mlp2_b, attout, out0, nullptr, nullptr, 1024, 1024, 512, 1024);
}